// Round 1
// baseline (742.157 us; speedup 1.0000x reference)
//
#include <hip/hip_runtime.h>

typedef short bf16x8 __attribute__((ext_vector_type(8)));
typedef float floatx4 __attribute__((ext_vector_type(4)));

#define MFMA16(a, b, c) __builtin_amdgcn_mfma_f32_16x16x32_bf16((a), (b), (c), 0, 0, 0)

__device__ __forceinline__ unsigned short f2bf(float f) {
    union { float f; unsigned int u; } v; v.f = f;
    unsigned int u = v.u;
    return (unsigned short)((u + 0x7FFFu + ((u >> 16) & 1u)) >> 16);
}

// ---------------------------------------------------------------- LayerNorm
// one block per row (H=2048), 256 threads x 8 elements
__global__ __launch_bounds__(256) void ln_kernel(
        const float* __restrict__ x, const float* __restrict__ g,
        const float* __restrict__ be, float* __restrict__ yo,
        unsigned short* __restrict__ yb) {
    int row = blockIdx.x, t = threadIdx.x;
    const float* xr = x + (size_t)row * 2048;
    float4 a = ((const float4*)xr)[2 * t];
    float4 b = ((const float4*)xr)[2 * t + 1];
    float s = a.x + a.y + a.z + a.w + b.x + b.y + b.z + b.w;
    float q = a.x * a.x + a.y * a.y + a.z * a.z + a.w * a.w +
              b.x * b.x + b.y * b.y + b.z * b.z + b.w * b.w;
    for (int m = 1; m < 64; m <<= 1) { s += __shfl_xor(s, m); q += __shfl_xor(q, m); }
    __shared__ float red[8];
    if ((t & 63) == 0) { red[t >> 6] = s; red[4 + (t >> 6)] = q; }
    __syncthreads();
    s = red[0] + red[1] + red[2] + red[3];
    q = red[4] + red[5] + red[6] + red[7];
    float mean = s * (1.0f / 2048.0f);
    float var = q * (1.0f / 2048.0f) - mean * mean;
    float rs = rsqrtf(var + 1e-12f);
    float4 g0 = ((const float4*)g)[2 * t], g1 = ((const float4*)g)[2 * t + 1];
    float4 b0 = ((const float4*)be)[2 * t], b1 = ((const float4*)be)[2 * t + 1];
    float4 y0, y1;
    y0.x = (a.x - mean) * rs * g0.x + b0.x;
    y0.y = (a.y - mean) * rs * g0.y + b0.y;
    y0.z = (a.z - mean) * rs * g0.z + b0.z;
    y0.w = (a.w - mean) * rs * g0.w + b0.w;
    y1.x = (b.x - mean) * rs * g1.x + b1.x;
    y1.y = (b.y - mean) * rs * g1.y + b1.y;
    y1.z = (b.z - mean) * rs * g1.z + b1.z;
    y1.w = (b.w - mean) * rs * g1.w + b1.w;
    float* yr = yo + (size_t)row * 2048;
    ((float4*)yr)[2 * t] = y0;
    ((float4*)yr)[2 * t + 1] = y1;
    union { unsigned short u[8]; uint4 v; } pk;
    pk.u[0] = f2bf(y0.x); pk.u[1] = f2bf(y0.y); pk.u[2] = f2bf(y0.z); pk.u[3] = f2bf(y0.w);
    pk.u[4] = f2bf(y1.x); pk.u[5] = f2bf(y1.y); pk.u[6] = f2bf(y1.z); pk.u[7] = f2bf(y1.w);
    *(uint4*)(yb + (size_t)row * 2048 + t * 8) = pk.v;
}

// ------------------------------------------- batched transpose fp32 -> bf16
// src [z][K][N] fp32 row-major  ->  dst [z][N][K] bf16
// grid: (N/64, K/64, batch), 256 threads, 64x64 tiles
__global__ __launch_bounds__(256) void transpose_cvt(
        const float* __restrict__ src, unsigned short* __restrict__ dst,
        int K, int N) {
    __shared__ unsigned short tile[64][73];
    int n0 = blockIdx.x * 64, k0 = blockIdx.y * 64;
    size_t bo = (size_t)blockIdx.z * K * N;
    int t = threadIdx.x;
    for (int p = 0; p < 4; p++) {
        int idx = p * 256 + t; int r = idx >> 4; int c = (idx & 15) * 4;
        float4 v = *(const float4*)(src + bo + (size_t)(k0 + r) * N + n0 + c);
        tile[r][c] = f2bf(v.x); tile[r][c + 1] = f2bf(v.y);
        tile[r][c + 2] = f2bf(v.z); tile[r][c + 3] = f2bf(v.w);
    }
    __syncthreads();
    for (int p = 0; p < 4; p++) {
        int idx = p * 256 + t; int n = idx >> 4; int c = (idx & 15) * 4;
        ushort4 o;
        o.x = tile[c][n]; o.y = tile[c + 1][n];
        o.z = tile[c + 2][n]; o.w = tile[c + 3][n];
        *(ushort4*)(dst + bo + (size_t)(n0 + n) * K + k0 + c) = o;
    }
}

// ---------------------------------------------------------------- QKV GEMM
// C[4096][6144] = A[4096][2048](bf16) @ Bt[6144][2048]^T (bf16) + bias
// 128x128 tile, BK=64, 4 waves (2x2), each wave 64x64 = 4x4 frags of 16x16
__global__ __launch_bounds__(256) void gemm_qkv(
        const unsigned short* __restrict__ A, const unsigned short* __restrict__ Bt,
        const float* __restrict__ bias, float* __restrict__ ko,
        float* __restrict__ vo, unsigned short* __restrict__ qws) {
    __shared__ unsigned short As[128 * 72];
    __shared__ unsigned short Bs[128 * 72];
    int m0 = blockIdx.y * 128, n0 = blockIdx.x * 128;
    int t = threadIdx.x;
    int wave = t >> 6, lane = t & 63, ln15 = lane & 15, quad = lane >> 4;
    int wm = wave >> 1, wn = wave & 1;
    floatx4 acc[4][4] = {};
    for (int k0 = 0; k0 < 2048; k0 += 64) {
        for (int p = 0; p < 4; p++) {
            int idx = p * 256 + t; int r = idx >> 3; int c = (idx & 7) * 8;
            *(uint4*)&As[r * 72 + c] = *(const uint4*)(A + (size_t)(m0 + r) * 2048 + k0 + c);
            *(uint4*)&Bs[r * 72 + c] = *(const uint4*)(Bt + (size_t)(n0 + r) * 2048 + k0 + c);
        }
        __syncthreads();
        for (int ks = 0; ks < 2; ks++) {
            bf16x8 af[4], bf[4];
            for (int i = 0; i < 4; i++)
                af[i] = *(const bf16x8*)&As[(wm * 64 + i * 16 + ln15) * 72 + ks * 32 + quad * 8];
            for (int i = 0; i < 4; i++)
                bf[i] = *(const bf16x8*)&Bs[(wn * 64 + i * 16 + ln15) * 72 + ks * 32 + quad * 8];
            for (int mi = 0; mi < 4; mi++)
                for (int ni = 0; ni < 4; ni++)
                    acc[mi][ni] = MFMA16(af[mi], bf[ni], acc[mi][ni]);
        }
        __syncthreads();
    }
    for (int mi = 0; mi < 4; mi++) {
        int row = m0 + wm * 64 + mi * 16 + quad * 4;
        for (int ni = 0; ni < 4; ni++) {
            int col = n0 + wn * 64 + ni * 16 + ln15;
            float bv = bias[col];
            for (int r = 0; r < 4; r++) {
                float val = acc[mi][ni][r] + bv;
                int rr = row + r;
                int b = rr >> 11, s = rr & 2047;
                if (col < 2048) {
                    qws[(size_t)rr * 2048 + col] = f2bf(val);
                } else if (col < 4096) {
                    int cc = col - 2048; int h = cc >> 7, d = cc & 127;
                    ko[((size_t)(b * 16 + h) * 2048 + s) * 128 + d] = val;
                } else {
                    int cc = col - 4096; int h = cc >> 7, d = cc & 127;
                    vo[((size_t)(b * 16 + h) * 2048 + s) * 128 + d] = val;
                }
            }
        }
    }
}

// ------------------------------------------------------------- output GEMM
// out[4096][2048] = ctx[4096][2048](fp32, cvt on stage) @ owT[2048][2048]^T
__global__ __launch_bounds__(256) void gemm_out(
        const float* __restrict__ Actx, const unsigned short* __restrict__ Bt,
        float* __restrict__ out) {
    __shared__ unsigned short As[128 * 72];
    __shared__ unsigned short Bs[128 * 72];
    int m0 = blockIdx.y * 128, n0 = blockIdx.x * 128;
    int t = threadIdx.x;
    int wave = t >> 6, lane = t & 63, ln15 = lane & 15, quad = lane >> 4;
    int wm = wave >> 1, wn = wave & 1;
    floatx4 acc[4][4] = {};
    for (int k0 = 0; k0 < 2048; k0 += 64) {
        for (int p = 0; p < 4; p++) {
            int idx = p * 256 + t; int r = idx >> 3; int c = (idx & 7) * 8;
            const float* ap = Actx + (size_t)(m0 + r) * 2048 + k0 + c;
            float4 u0 = ((const float4*)ap)[0], u1 = ((const float4*)ap)[1];
            union { unsigned short u[8]; uint4 v; } pk;
            pk.u[0] = f2bf(u0.x); pk.u[1] = f2bf(u0.y); pk.u[2] = f2bf(u0.z); pk.u[3] = f2bf(u0.w);
            pk.u[4] = f2bf(u1.x); pk.u[5] = f2bf(u1.y); pk.u[6] = f2bf(u1.z); pk.u[7] = f2bf(u1.w);
            *(uint4*)&As[r * 72 + c] = pk.v;
            *(uint4*)&Bs[r * 72 + c] = *(const uint4*)(Bt + (size_t)(n0 + r) * 2048 + k0 + c);
        }
        __syncthreads();
        for (int ks = 0; ks < 2; ks++) {
            bf16x8 af[4], bf[4];
            for (int i = 0; i < 4; i++)
                af[i] = *(const bf16x8*)&As[(wm * 64 + i * 16 + ln15) * 72 + ks * 32 + quad * 8];
            for (int i = 0; i < 4; i++)
                bf[i] = *(const bf16x8*)&Bs[(wn * 64 + i * 16 + ln15) * 72 + ks * 32 + quad * 8];
            for (int mi = 0; mi < 4; mi++)
                for (int ni = 0; ni < 4; ni++)
                    acc[mi][ni] = MFMA16(af[mi], bf[ni], acc[mi][ni]);
        }
        __syncthreads();
    }
    for (int mi = 0; mi < 4; mi++) {
        int row = m0 + wm * 64 + mi * 16 + quad * 4;
        for (int ni = 0; ni < 4; ni++) {
            int col = n0 + wn * 64 + ni * 16 + ln15;
            for (int r = 0; r < 4; r++)
                out[(size_t)(row + r) * 2048 + col] = acc[mi][ni][r];
        }
    }
}

// ---------------------------------------------------------- flash attention
// grid (S/64, HEADS, B); 4 waves/block, wave w owns q rows Q0+16w..+15
__global__ __launch_bounds__(256) void attn_kernel(
        const unsigned short* __restrict__ qws, const float* __restrict__ kf32,
        const unsigned short* __restrict__ vT, const float* __restrict__ mask,
        float* __restrict__ ctxo) {
    __shared__ unsigned short Ks[64 * 136];   // [s_local][d] + pad
    __shared__ unsigned short Vt[128 * 72];   // [d][s_local] + pad
    __shared__ unsigned short Pl[4 * 16 * 72]; // per-wave P, [m][s_local]
    int qt = blockIdx.x, h = blockIdx.y, b = blockIdx.z;
    int t = threadIdx.x, wave = t >> 6, lane = t & 63, ln15 = lane & 15, quad = lane >> 4;
    int Q0 = qt * 64;
    const float scale = 0.08838834764831845f;  // 1/sqrt(128)

    bf16x8 qf[4];
    const unsigned short* qbase =
        qws + ((size_t)(b * 2048 + Q0 + wave * 16 + ln15)) * 2048 + h * 128;
    for (int ks = 0; ks < 4; ks++)
        qf[ks] = *(const bf16x8*)(qbase + ks * 32 + quad * 8);

    float m_r[4], l_r[4];
    floatx4 o[8] = {};
    for (int r = 0; r < 4; r++) { m_r[r] = -1e30f; l_r[r] = 0.0f; }

    const float* kb = kf32 + (size_t)(b * 16 + h) * 2048 * 128;
    const unsigned short* vTb = vT + (size_t)(b * 16 + h) * 128 * 2048;
    const float* mb = mask + (size_t)b * 2048;
    int nkt = qt + 1;

    for (int kt = 0; kt < nkt; kt++) {
        int c0 = kt * 64;
        // stage K tile (fp32 -> bf16)
        for (int p = 0; p < 4; p++) {
            int idx = p * 256 + t; int r = idx >> 4; int c = (idx & 15) * 8;
            const float* sp = kb + (size_t)(c0 + r) * 128 + c;
            float4 u0 = ((const float4*)sp)[0], u1 = ((const float4*)sp)[1];
            union { unsigned short u[8]; uint4 v; } pk;
            pk.u[0] = f2bf(u0.x); pk.u[1] = f2bf(u0.y); pk.u[2] = f2bf(u0.z); pk.u[3] = f2bf(u0.w);
            pk.u[4] = f2bf(u1.x); pk.u[5] = f2bf(u1.y); pk.u[6] = f2bf(u1.z); pk.u[7] = f2bf(u1.w);
            *(uint4*)&Ks[r * 136 + c] = pk.v;
        }
        // stage V tile (already transposed bf16 in ws)
        for (int p = 0; p < 4; p++) {
            int idx = p * 256 + t; int d = idx >> 3; int sg = (idx & 7) * 8;
            *(uint4*)&Vt[d * 72 + sg] = *(const uint4*)(vTb + (size_t)d * 2048 + c0 + sg);
        }
        __syncthreads();

        // S = Q @ K^T  (16 x 64 per wave)
        floatx4 cs[4] = {};
        for (int ks = 0; ks < 4; ks++)
            for (int ni = 0; ni < 4; ni++) {
                bf16x8 kfr = *(const bf16x8*)&Ks[(ni * 16 + ln15) * 136 + ks * 32 + quad * 8];
                cs[ni] = MFMA16(qf[ks], kfr, cs[ni]);
            }

        // online softmax
        float sv[4][4];
        float mt[4] = {-1e30f, -1e30f, -1e30f, -1e30f};
        for (int ni = 0; ni < 4; ni++) {
            int cg = c0 + ni * 16 + ln15;
            float mk = mb[cg];
            for (int r = 0; r < 4; r++) {
                int qg = Q0 + wave * 16 + quad * 4 + r;
                float v = (cg <= qg) ? cs[ni][r] * scale + mk : -10000.0f;
                sv[ni][r] = v;
                mt[r] = fmaxf(mt[r], v);
            }
        }
        for (int m = 1; m < 16; m <<= 1)
            for (int r = 0; r < 4; r++) mt[r] = fmaxf(mt[r], __shfl_xor(mt[r], m));
        float alpha[4], lt[4];
        for (int r = 0; r < 4; r++) {
            float mn = fmaxf(m_r[r], mt[r]);
            alpha[r] = __expf(m_r[r] - mn);
            m_r[r] = mn;
            lt[r] = 0.0f;
        }
        for (int ni = 0; ni < 4; ni++)
            for (int r = 0; r < 4; r++) {
                float p = __expf(sv[ni][r] - m_r[r]);
                sv[ni][r] = p;
                lt[r] += p;
            }
        for (int m = 1; m < 16; m <<= 1)
            for (int r = 0; r < 4; r++) lt[r] += __shfl_xor(lt[r], m);
        for (int r = 0; r < 4; r++) l_r[r] = l_r[r] * alpha[r] + lt[r];
        for (int nj = 0; nj < 8; nj++)
            for (int r = 0; r < 4; r++) o[nj][r] *= alpha[r];

        // P (C-layout) -> LDS -> A-layout
        unsigned short* pw = &Pl[wave * 16 * 72];
        for (int ni = 0; ni < 4; ni++)
            for (int r = 0; r < 4; r++)
                pw[(quad * 4 + r) * 72 + ni * 16 + ln15] = f2bf(sv[ni][r]);
        // wave-internal LDS dependency; compiler inserts lgkmcnt wait

        for (int ks2 = 0; ks2 < 2; ks2++) {
            bf16x8 pf = *(const bf16x8*)&Pl[(wave * 16 + ln15) * 72 + ks2 * 32 + quad * 8];
            for (int nj = 0; nj < 8; nj++) {
                bf16x8 vf = *(const bf16x8*)&Vt[(nj * 16 + ln15) * 72 + ks2 * 32 + quad * 8];
                o[nj] = MFMA16(pf, vf, o[nj]);
            }
        }
        __syncthreads();
    }

    float rl[4];
    for (int r = 0; r < 4; r++) rl[r] = 1.0f / l_r[r];
    for (int nj = 0; nj < 8; nj++)
        for (int r = 0; r < 4; r++) {
            int s = Q0 + wave * 16 + quad * 4 + r;
            ctxo[((size_t)(b * 2048 + s)) * 2048 + h * 128 + nj * 16 + ln15] = o[nj][r] * rl[r];
        }
}

extern "C" void kernel_launch(void* const* d_in, const int* in_sizes, int n_in,
                              void* d_out, int out_size, void* d_ws, size_t ws_size,
                              hipStream_t stream) {
    const float* x      = (const float*)d_in[0];
    const float* mask   = (const float*)d_in[1];
    const float* qkvw   = (const float*)d_in[2];
    const float* qkvb   = (const float*)d_in[3];
    const float* ow     = (const float*)d_in[4];
    const float* norm_w = (const float*)d_in[5];
    const float* norm_b = (const float*)d_in[6];

    float* out      = (float*)d_out;             // [B,S,H]
    float* k_out    = out + 8388608;             // [B,Hd,S,dh]
    float* v_out    = out + 16777216;            // [B,Hd,S,dh]
    float* ctx_out  = out + 25165824;            // [B,S,H]
    float* norm_out = out + 33554432;            // [B,S,H]

    unsigned short* ws    = (unsigned short*)d_ws;
    unsigned short* xn    = ws;                        // 8,388,608  bf16
    unsigned short* qkvwT = ws + 8388608;              // 12,582,912 bf16 [6144][2048]
    unsigned short* owT   = ws + 8388608 + 12582912;   // 4,194,304  bf16 [2048][2048]
    unsigned short* qws   = owT + 4194304;             // 8,388,608  bf16 [B*S][H]
    unsigned short* vT    = qws + 8388608;             // 8,388,608  bf16 [B*Hd][dh][S]

    ln_kernel<<<4096, 256, 0, stream>>>(x, norm_w, norm_b, norm_out, xn);
    transpose_cvt<<<dim3(96, 32, 1), 256, 0, stream>>>(qkvw, qkvwT, 2048, 6144);
    transpose_cvt<<<dim3(32, 32, 1), 256, 0, stream>>>(ow, owT, 2048, 2048);
    gemm_qkv<<<dim3(48, 32), 256, 0, stream>>>(xn, qkvwT, qkvb, k_out, v_out, qws);
    transpose_cvt<<<dim3(2, 32, 32), 256, 0, stream>>>(v_out, vT, 2048, 128);
    attn_kernel<<<dim3(32, 16, 2), 256, 0, stream>>>(qws, k_out, vT, mask, ctx_out);
    gemm_out<<<dim3(16, 32), 256, 0, stream>>>(ctx_out, owT, out);
}

// Round 2
// 558.251 us; speedup vs baseline: 1.3294x; 1.3294x over previous
//
#include <hip/hip_runtime.h>

typedef short bf16x8 __attribute__((ext_vector_type(8)));
typedef float floatx4 __attribute__((ext_vector_type(4)));

#define MFMA16(a, b, c) __builtin_amdgcn_mfma_f32_16x16x32_bf16((a), (b), (c), 0, 0, 0)

__device__ __forceinline__ unsigned short f2bf(float f) {
    union { float f; unsigned int u; } v; v.f = f;
    unsigned int u = v.u;
    return (unsigned short)((u + 0x7FFFu + ((u >> 16) & 1u)) >> 16);
}

// async global->LDS, 16B per lane; lds base must be wave-uniform (m97 pattern)
__device__ __forceinline__ void gld_lds16(const void* g, void* l) {
    __builtin_amdgcn_global_load_lds(
        (const __attribute__((address_space(1))) unsigned int*)g,
        (__attribute__((address_space(3))) unsigned int*)l, 16, 0, 0);
}

// ---------------------------------------------------------------- LayerNorm
__global__ __launch_bounds__(256) void ln_kernel(
        const float* __restrict__ x, const float* __restrict__ g,
        const float* __restrict__ be, float* __restrict__ yo,
        unsigned short* __restrict__ yb) {
    int row = blockIdx.x, t = threadIdx.x;
    const float* xr = x + (size_t)row * 2048;
    float4 a = ((const float4*)xr)[2 * t];
    float4 b = ((const float4*)xr)[2 * t + 1];
    float s = a.x + a.y + a.z + a.w + b.x + b.y + b.z + b.w;
    float q = a.x * a.x + a.y * a.y + a.z * a.z + a.w * a.w +
              b.x * b.x + b.y * b.y + b.z * b.z + b.w * b.w;
    for (int m = 1; m < 64; m <<= 1) { s += __shfl_xor(s, m); q += __shfl_xor(q, m); }
    __shared__ float red[8];
    if ((t & 63) == 0) { red[t >> 6] = s; red[4 + (t >> 6)] = q; }
    __syncthreads();
    s = red[0] + red[1] + red[2] + red[3];
    q = red[4] + red[5] + red[6] + red[7];
    float mean = s * (1.0f / 2048.0f);
    float var = q * (1.0f / 2048.0f) - mean * mean;
    float rs = rsqrtf(var + 1e-12f);
    float4 g0 = ((const float4*)g)[2 * t], g1 = ((const float4*)g)[2 * t + 1];
    float4 b0 = ((const float4*)be)[2 * t], b1 = ((const float4*)be)[2 * t + 1];
    float4 y0, y1;
    y0.x = (a.x - mean) * rs * g0.x + b0.x;
    y0.y = (a.y - mean) * rs * g0.y + b0.y;
    y0.z = (a.z - mean) * rs * g0.z + b0.z;
    y0.w = (a.w - mean) * rs * g0.w + b0.w;
    y1.x = (b.x - mean) * rs * g1.x + b1.x;
    y1.y = (b.y - mean) * rs * g1.y + b1.y;
    y1.z = (b.z - mean) * rs * g1.z + b1.z;
    y1.w = (b.w - mean) * rs * g1.w + b1.w;
    float* yr = yo + (size_t)row * 2048;
    ((float4*)yr)[2 * t] = y0;
    ((float4*)yr)[2 * t + 1] = y1;
    union { unsigned short u[8]; uint4 v; } pk;
    pk.u[0] = f2bf(y0.x); pk.u[1] = f2bf(y0.y); pk.u[2] = f2bf(y0.z); pk.u[3] = f2bf(y0.w);
    pk.u[4] = f2bf(y1.x); pk.u[5] = f2bf(y1.y); pk.u[6] = f2bf(y1.z); pk.u[7] = f2bf(y1.w);
    *(uint4*)(yb + (size_t)row * 2048 + t * 8) = pk.v;
}

// ------------------------------------------- batched transpose fp32 -> bf16
__global__ __launch_bounds__(256) void transpose_cvt(
        const float* __restrict__ src, unsigned short* __restrict__ dst,
        int K, int N) {
    __shared__ unsigned short tile[64][73];
    int n0 = blockIdx.x * 64, k0 = blockIdx.y * 64;
    size_t bo = (size_t)blockIdx.z * K * N;
    int t = threadIdx.x;
    for (int p = 0; p < 4; p++) {
        int idx = p * 256 + t; int r = idx >> 4; int c = (idx & 15) * 4;
        float4 v = *(const float4*)(src + bo + (size_t)(k0 + r) * N + n0 + c);
        tile[r][c] = f2bf(v.x); tile[r][c + 1] = f2bf(v.y);
        tile[r][c + 2] = f2bf(v.z); tile[r][c + 3] = f2bf(v.w);
    }
    __syncthreads();
    for (int p = 0; p < 4; p++) {
        int idx = p * 256 + t; int n = idx >> 4; int c = (idx & 15) * 4;
        ushort4 o;
        o.x = tile[c][n]; o.y = tile[c + 1][n];
        o.z = tile[c + 2][n]; o.w = tile[c + 3][n];
        *(ushort4*)(dst + bo + (size_t)(n0 + n) * K + k0 + c) = o;
    }
}

// ---------------------------------------------------------------- QKV GEMM
// m97-style: global_load_lds width 16, unpadded LDS (stride 64)
__global__ __launch_bounds__(256) void gemm_qkv(
        const unsigned short* __restrict__ A, const unsigned short* __restrict__ Bt,
        const float* __restrict__ bias, float* __restrict__ ko,
        float* __restrict__ vo, unsigned short* __restrict__ qws,
        unsigned short* __restrict__ kbf) {
    __shared__ unsigned short As[128 * 64];
    __shared__ unsigned short Bs[128 * 64];
    int m0 = blockIdx.y * 128, n0 = blockIdx.x * 128;
    int t = threadIdx.x;
    int wave = t >> 6, lane = t & 63, ln15 = lane & 15, quad = lane >> 4;
    int wm = wave >> 1, wn = wave & 1;
    floatx4 acc[4][4] = {};
    for (int k0 = 0; k0 < 2048; k0 += 64) {
        for (int p = 0; p < 4; p++) {
            int idx = p * 256 + t; int r = idx >> 3; int c = (idx & 7) * 8;
            gld_lds16(A + (size_t)(m0 + r) * 2048 + k0 + c, As + p * 2048 + wave * 512);
            gld_lds16(Bt + (size_t)(n0 + r) * 2048 + k0 + c, Bs + p * 2048 + wave * 512);
        }
        __syncthreads();
        for (int ks = 0; ks < 2; ks++) {
            bf16x8 af[4], bfr[4];
            for (int i = 0; i < 4; i++)
                af[i] = *(const bf16x8*)&As[(wm * 64 + i * 16 + ln15) * 64 + ks * 32 + quad * 8];
            for (int i = 0; i < 4; i++)
                bfr[i] = *(const bf16x8*)&Bs[(wn * 64 + i * 16 + ln15) * 64 + ks * 32 + quad * 8];
            for (int mi = 0; mi < 4; mi++)
                for (int ni = 0; ni < 4; ni++)
                    acc[mi][ni] = MFMA16(af[mi], bfr[ni], acc[mi][ni]);
        }
        __syncthreads();
    }
    for (int mi = 0; mi < 4; mi++) {
        int row = m0 + wm * 64 + mi * 16 + quad * 4;
        for (int ni = 0; ni < 4; ni++) {
            int col = n0 + wn * 64 + ni * 16 + ln15;
            float bv = bias[col];
            for (int r = 0; r < 4; r++) {
                float val = acc[mi][ni][r] + bv;
                int rr = row + r;
                int b = rr >> 11, s = rr & 2047;
                if (col < 2048) {
                    qws[(size_t)rr * 2048 + col] = f2bf(val);
                } else if (col < 4096) {
                    int cc = col - 2048; int h = cc >> 7, d = cc & 127;
                    size_t o = ((size_t)(b * 16 + h) * 2048 + s) * 128 + d;
                    ko[o] = val;
                    kbf[o] = f2bf(val);
                } else {
                    int cc = col - 4096; int h = cc >> 7, d = cc & 127;
                    vo[((size_t)(b * 16 + h) * 2048 + s) * 128 + d] = val;
                }
            }
        }
    }
}

// ------------------------------------------------------------- output GEMM
__global__ __launch_bounds__(256) void gemm_out(
        const float* __restrict__ Actx, const unsigned short* __restrict__ Bt,
        float* __restrict__ out) {
    __shared__ unsigned short As[128 * 72];
    __shared__ unsigned short Bs[128 * 72];
    int m0 = blockIdx.y * 128, n0 = blockIdx.x * 128;
    int t = threadIdx.x;
    int wave = t >> 6, lane = t & 63, ln15 = lane & 15, quad = lane >> 4;
    int wm = wave >> 1, wn = wave & 1;
    floatx4 acc[4][4] = {};
    for (int k0 = 0; k0 < 2048; k0 += 64) {
        for (int p = 0; p < 4; p++) {
            int idx = p * 256 + t; int r = idx >> 3; int c = (idx & 7) * 8;
            const float* ap = Actx + (size_t)(m0 + r) * 2048 + k0 + c;
            float4 u0 = ((const float4*)ap)[0], u1 = ((const float4*)ap)[1];
            union { unsigned short u[8]; uint4 v; } pk;
            pk.u[0] = f2bf(u0.x); pk.u[1] = f2bf(u0.y); pk.u[2] = f2bf(u0.z); pk.u[3] = f2bf(u0.w);
            pk.u[4] = f2bf(u1.x); pk.u[5] = f2bf(u1.y); pk.u[6] = f2bf(u1.z); pk.u[7] = f2bf(u1.w);
            *(uint4*)&As[r * 72 + c] = pk.v;
            *(uint4*)&Bs[r * 72 + c] = *(const uint4*)(Bt + (size_t)(n0 + r) * 2048 + k0 + c);
        }
        __syncthreads();
        for (int ks = 0; ks < 2; ks++) {
            bf16x8 af[4], bfr[4];
            for (int i = 0; i < 4; i++)
                af[i] = *(const bf16x8*)&As[(wm * 64 + i * 16 + ln15) * 72 + ks * 32 + quad * 8];
            for (int i = 0; i < 4; i++)
                bfr[i] = *(const bf16x8*)&Bs[(wn * 64 + i * 16 + ln15) * 72 + ks * 32 + quad * 8];
            for (int mi = 0; mi < 4; mi++)
                for (int ni = 0; ni < 4; ni++)
                    acc[mi][ni] = MFMA16(af[mi], bfr[ni], acc[mi][ni]);
        }
        __syncthreads();
    }
    for (int mi = 0; mi < 4; mi++) {
        int row = m0 + wm * 64 + mi * 16 + quad * 4;
        for (int ni = 0; ni < 4; ni++) {
            int col = n0 + wn * 64 + ni * 16 + ln15;
            for (int r = 0; r < 4; r++)
                out[(size_t)(row + r) * 2048 + col] = acc[mi][ni][r];
        }
    }
}

// ---------------------------------------------------------- flash attention
// grid (16, HEADS, B); block handles q-tile pair (j, 31-j) -> 33 iters each
__global__ __launch_bounds__(256) void attn_kernel(
        const unsigned short* __restrict__ qws, const unsigned short* __restrict__ kbf,
        const unsigned short* __restrict__ vT, const float* __restrict__ mask,
        float* __restrict__ ctxo) {
    __shared__ unsigned short Ks[64 * 136];
    __shared__ unsigned short Vt[128 * 72];
    __shared__ unsigned short Pl[4 * 16 * 72];
    int jp = blockIdx.x, h = blockIdx.y, b = blockIdx.z;
    int t = threadIdx.x, wave = t >> 6, lane = t & 63, ln15 = lane & 15, quad = lane >> 4;
    const float scale = 0.08838834764831845f;  // 1/sqrt(128)

    const unsigned short* kb = kbf + (size_t)(b * 16 + h) * 2048 * 128;
    const unsigned short* vTb = vT + (size_t)(b * 16 + h) * 128 * 2048;
    const float* mb = mask + (size_t)b * 2048;

    for (int half = 0; half < 2; half++) {
        int qt = half ? (31 - jp) : jp;
        int Q0 = qt * 64;

        bf16x8 qf[4];
        const unsigned short* qbase =
            qws + ((size_t)(b * 2048 + Q0 + wave * 16 + ln15)) * 2048 + h * 128;
        for (int ks = 0; ks < 4; ks++)
            qf[ks] = *(const bf16x8*)(qbase + ks * 32 + quad * 8);

        float m_r[4], l_r[4];
        floatx4 o[8] = {};
        for (int r = 0; r < 4; r++) { m_r[r] = -1e30f; l_r[r] = 0.0f; }

        int nkt = qt + 1;
        for (int kt = 0; kt < nkt; kt++) {
            int c0 = kt * 64;
            // stage K tile (bf16 direct)
            for (int p = 0; p < 4; p++) {
                int idx = p * 256 + t; int r = idx >> 4; int c = (idx & 15) * 8;
                *(uint4*)&Ks[r * 136 + c] = *(const uint4*)(kb + (size_t)(c0 + r) * 128 + c);
            }
            // stage V tile (transposed bf16)
            for (int p = 0; p < 4; p++) {
                int idx = p * 256 + t; int d = idx >> 3; int sg = (idx & 7) * 8;
                *(uint4*)&Vt[d * 72 + sg] = *(const uint4*)(vTb + (size_t)d * 2048 + c0 + sg);
            }
            __syncthreads();

            // S = Q @ K^T  (16 x 64 per wave)
            floatx4 cs[4] = {};
            for (int ks = 0; ks < 4; ks++)
                for (int ni = 0; ni < 4; ni++) {
                    bf16x8 kfr = *(const bf16x8*)&Ks[(ni * 16 + ln15) * 136 + ks * 32 + quad * 8];
                    cs[ni] = MFMA16(qf[ks], kfr, cs[ni]);
                }

            // online softmax
            float sv[4][4];
            float mt[4] = {-1e30f, -1e30f, -1e30f, -1e30f};
            if (kt == qt) {
                for (int ni = 0; ni < 4; ni++) {
                    int cg = c0 + ni * 16 + ln15;
                    float mk = mb[cg];
                    for (int r = 0; r < 4; r++) {
                        int qg = Q0 + wave * 16 + quad * 4 + r;
                        float v = (cg <= qg) ? cs[ni][r] * scale + mk : -10000.0f;
                        sv[ni][r] = v;
                        mt[r] = fmaxf(mt[r], v);
                    }
                }
            } else {
                for (int ni = 0; ni < 4; ni++) {
                    float mk = mb[c0 + ni * 16 + ln15];
                    for (int r = 0; r < 4; r++) {
                        float v = cs[ni][r] * scale + mk;
                        sv[ni][r] = v;
                        mt[r] = fmaxf(mt[r], v);
                    }
                }
            }
            for (int m = 1; m < 16; m <<= 1)
                for (int r = 0; r < 4; r++) mt[r] = fmaxf(mt[r], __shfl_xor(mt[r], m));
            float alpha[4], lt[4];
            for (int r = 0; r < 4; r++) {
                float mn = fmaxf(m_r[r], mt[r]);
                alpha[r] = __expf(m_r[r] - mn);
                m_r[r] = mn;
                lt[r] = 0.0f;
            }
            for (int ni = 0; ni < 4; ni++)
                for (int r = 0; r < 4; r++) {
                    float p = __expf(sv[ni][r] - m_r[r]);
                    sv[ni][r] = p;
                    lt[r] += p;
                }
            for (int m = 1; m < 16; m <<= 1)
                for (int r = 0; r < 4; r++) lt[r] += __shfl_xor(lt[r], m);
            for (int r = 0; r < 4; r++) l_r[r] = l_r[r] * alpha[r] + lt[r];
            for (int nj = 0; nj < 8; nj++)
                for (int r = 0; r < 4; r++) o[nj][r] *= alpha[r];

            // P (C-layout) -> LDS -> A-layout (wave-private region)
            unsigned short* pw = &Pl[wave * 16 * 72];
            for (int ni = 0; ni < 4; ni++)
                for (int r = 0; r < 4; r++)
                    pw[(quad * 4 + r) * 72 + ni * 16 + ln15] = f2bf(sv[ni][r]);

            for (int ks2 = 0; ks2 < 2; ks2++) {
                bf16x8 pf = *(const bf16x8*)&Pl[(wave * 16 + ln15) * 72 + ks2 * 32 + quad * 8];
                for (int nj = 0; nj < 8; nj++) {
                    bf16x8 vf = *(const bf16x8*)&Vt[(nj * 16 + ln15) * 72 + ks2 * 32 + quad * 8];
                    o[nj] = MFMA16(pf, vf, o[nj]);
                }
            }
            __syncthreads();
        }

        float rl[4];
        for (int r = 0; r < 4; r++) rl[r] = 1.0f / l_r[r];
        for (int nj = 0; nj < 8; nj++)
            for (int r = 0; r < 4; r++) {
                int s = Q0 + wave * 16 + quad * 4 + r;
                ctxo[((size_t)(b * 2048 + s)) * 2048 + h * 128 + nj * 16 + ln15] = o[nj][r] * rl[r];
            }
    }
}

extern "C" void kernel_launch(void* const* d_in, const int* in_sizes, int n_in,
                              void* d_out, int out_size, void* d_ws, size_t ws_size,
                              hipStream_t stream) {
    const float* x      = (const float*)d_in[0];
    const float* mask   = (const float*)d_in[1];
    const float* qkvw   = (const float*)d_in[2];
    const float* qkvb   = (const float*)d_in[3];
    const float* ow     = (const float*)d_in[4];
    const float* norm_w = (const float*)d_in[5];
    const float* norm_b = (const float*)d_in[6];

    float* out      = (float*)d_out;             // [B,S,H]
    float* k_out    = out + 8388608;             // [B,Hd,S,dh]
    float* v_out    = out + 16777216;            // [B,Hd,S,dh]
    float* ctx_out  = out + 25165824;            // [B,S,H]
    float* norm_out = out + 33554432;            // [B,S,H]

    unsigned short* ws    = (unsigned short*)d_ws;
    unsigned short* xn    = ws;                        // 8,388,608  bf16
    unsigned short* qkvwT = ws + 8388608;              // 12,582,912 bf16 [6144][2048]
    unsigned short* owT   = ws + 8388608 + 12582912;   // 4,194,304  bf16 [2048][2048]
    unsigned short* qws   = owT + 4194304;             // 8,388,608  bf16 [B*S][H]
    unsigned short* vT    = qws + 8388608;             // 8,388,608  bf16 [B*Hd][dh][S]
    unsigned short* kbf   = vT + 8388608;              // 8,388,608  bf16 [B*Hd][S][dh]

    ln_kernel<<<4096, 256, 0, stream>>>(x, norm_w, norm_b, norm_out, xn);
    transpose_cvt<<<dim3(96, 32, 1), 256, 0, stream>>>(qkvw, qkvwT, 2048, 6144);
    transpose_cvt<<<dim3(32, 32, 1), 256, 0, stream>>>(ow, owT, 2048, 2048);
    gemm_qkv<<<dim3(48, 32), 256, 0, stream>>>(xn, qkvwT, qkvb, k_out, v_out, qws, kbf);
    transpose_cvt<<<dim3(2, 32, 32), 256, 0, stream>>>(v_out, vT, 2048, 128);
    attn_kernel<<<dim3(16, 16, 2), 256, 0, stream>>>(qws, kbf, vT, mask, ctx_out);
    gemm_out<<<dim3(16, 32), 256, 0, stream>>>(ctx_out, owT, out);
}